// Round 8
// baseline (165.899 us; speedup 1.0000x reference)
//
#include <hip/hip_runtime.h>
#include <hip/hip_bf16.h>

#define C 48
#define HH 192
#define WW 192
#define HP 96
#define WP 96
#define NP 9216   // 96*96

// ws layout (float offsets) — R4 layout + O4 appended
#define OFF_X     0         // x (pooled): [48][9216] f32
#define OFF_O     442368    // (unused legacy slot, kept for layout stability)
#define OFF_QB    1032192   // QB: [9216][16] bf16
#define OFF_KB    1105920   // KB: [9216][16] bf16 (pre-scaled by log2e)
#define OFF_VB    1179648   // VB: [64][9216] bf16 (row 48=1.0, 49..63=0)
#define OFF_XTP   1474560   // XTP: [98*98][64] bf16, halo+ci-pad zeros
#define OFF_WB    1781888   // WB: [16][48][64] bf16
#define OFF_O4    1806464   // O4: [4][9216][64] f32 (atomic partial copies)
// total floats: 1806464 + 2359296 = 4165760 (16.66 MB; ws proven >= 23.7 MB)

typedef __attribute__((ext_vector_type(4))) short s16x4;
typedef __attribute__((ext_vector_type(8))) short s16x8;
typedef __attribute__((ext_vector_type(4))) float f32x4;

#if __has_builtin(__builtin_amdgcn_mfma_f32_16x16x16bf16_1k)
static __device__ inline f32x4 mfma16(s16x4 a, s16x4 b, f32x4 c) {
    return __builtin_amdgcn_mfma_f32_16x16x16bf16_1k(a, b, c, 0, 0, 0);
}
#else
static __device__ inline f32x4 mfma16(s16x4 a, s16x4 b, f32x4 c) {
    asm volatile("v_mfma_f32_16x16x16_bf16 %0, %1, %2, %0" : "+v"(c) : "v"(a), "v"(b));
    return c;
}
#endif

static __device__ inline f32x4 mfma32(s16x8 a, s16x8 b, f32x4 c) {
    return __builtin_amdgcn_mfma_f32_16x16x32_bf16(a, b, c, 0, 0, 0);
}

// raw v_exp_f32: computes 2^x (scores pre-scaled by log2e) — R4-proven codegen
static __device__ inline float fexp2(float x) {
    float r;
    asm("v_exp_f32 %0, %1" : "=v"(r) : "v"(x));
    return r;
}

static __device__ inline unsigned short f2bf(float f) {
    union { float f; unsigned u; } v; v.f = f;
    unsigned r = v.u + 0x7fff + ((v.u >> 16) & 1);
    return (unsigned short)(r >> 16);
}

static __device__ inline s16x4 pack_bf16x4(float a, float b, float c, float d) {
    __hip_bfloat162 h0 = __float22bfloat162_rn(make_float2(a, b));
    __hip_bfloat162 h1 = __float22bfloat162_rn(make_float2(c, d));
    union { unsigned u[2]; s16x4 v; } pu;
    pu.u[0] = *reinterpret_cast<unsigned*>(&h0);
    pu.u[1] = *reinterpret_cast<unsigned*>(&h1);
    return pu.v;
}

__global__ void pool_k(const float* __restrict__ in, float* __restrict__ x) {
    int idx = blockIdx.x * 256 + threadIdx.x;
    if (idx >= C * NP) return;
    int c = idx / NP, r = idx % NP;
    int y = r / WP, xx = r % WP;
    const float* p = in + (size_t)c * HH * WW + (2 * y) * WW + 2 * xx;
    x[idx] = 0.25f * (p[0] + p[1] + p[WW] + p[WW + 1]);
}

__global__ void qkvprep_k(const float* __restrict__ x,
                          const float* __restrict__ qw, const float* __restrict__ qb,
                          const float* __restrict__ kw, const float* __restrict__ kb,
                          const float* __restrict__ vw, const float* __restrict__ vb,
                          unsigned short* __restrict__ QB, unsigned short* __restrict__ KB,
                          unsigned short* __restrict__ VB) {
    int tid = blockIdx.x * 256 + threadIdx.x;   // 5*9216 threads
    int p = tid % NP;
    int g = tid / NP;
    float f[C];
#pragma unroll
    for (int c = 0; c < C; ++c) f[c] = x[c * NP + p];
    if (g == 0) {
#pragma unroll
        for (int o = 0; o < 16; ++o) {
            float a = qb[o];
#pragma unroll
            for (int c = 0; c < C; ++c) a += qw[o * C + c] * f[c];
            QB[p * 16 + o] = f2bf(a);
        }
    } else if (g == 1) {
        const float L2E = 1.4426950408889634f;
#pragma unroll
        for (int o = 0; o < 16; ++o) {
            float a = kb[o];
#pragma unroll
            for (int c = 0; c < C; ++c) a += kw[o * C + c] * f[c];
            KB[p * 16 + o] = f2bf(a * L2E);
        }
        VB[(size_t)48 * NP + p] = 0x3F80;  // bf16(1.0) -> den row
#pragma unroll
        for (int r = 49; r < 64; ++r) VB[(size_t)r * NP + p] = 0;
    } else {
        int c0 = (g - 2) * 16;
#pragma unroll
        for (int oo = 0; oo < 16; ++oo) {
            int o = c0 + oo;
            float a = vb[o];
#pragma unroll
            for (int c = 0; c < C; ++c) a += vw[o * C + c] * f[c];
            VB[(size_t)o * NP + p] = f2bf(a);
        }
    }
}

#define MBLKS 72
#define NSPL  32
#define NSTEP 18   // (NP/NSPL)/16
__global__ __launch_bounds__(256) void attn_k(const unsigned short* __restrict__ QB,
                                              const unsigned short* __restrict__ KB,
                                              const unsigned short* __restrict__ VB,
                                              float* __restrict__ O4) {
    const int lane = threadIdx.x & 63;
    const int lo = lane & 15, hi = lane >> 4;
    const int wv = threadIdx.x >> 6;
    const int mblk = blockIdx.x % MBLKS;
    const int nspl = blockIdx.x / MBLKS;
    const int mt0 = mblk * 128 + wv * 32;

    const s16x4 bq0 = *(const s16x4*)(KB + (size_t)(mt0 + lo) * 16 + 4 * hi);
    const s16x4 bq1 = *(const s16x4*)(KB + (size_t)(mt0 + 16 + lo) * 16 + 4 * hi);

    f32x4 o0[4], o1[4];
#pragma unroll
    for (int i = 0; i < 4; ++i) {
        o0[i] = (f32x4){0.f, 0.f, 0.f, 0.f};
        o1[i] = (f32x4){0.f, 0.f, 0.f, 0.f};
    }

    int n0 = nspl * (NP / NSPL);
    const unsigned short* qp = QB + (size_t)(n0 + lo) * 16 + 4 * hi;
    const unsigned short* vp = VB + (size_t)lo * NP + n0 + 4 * hi;

    // pipeline prologue
    s16x4 aq  = *(const s16x4*)qp;
    s16x4 bv0 = *(const s16x4*)(vp);
    s16x4 bv1 = *(const s16x4*)(vp + (size_t)16 * NP);
    s16x4 bv2 = *(const s16x4*)(vp + (size_t)32 * NP);
    s16x4 bv3 = *(const s16x4*)(vp + (size_t)48 * NP);

    for (int s = 0; s < NSTEP; ++s) {
        // prefetch next tile (tail over-read stays inside d_ws; values unused)
        qp += 16 * 16;
        vp += 16;
        s16x4 aqn  = *(const s16x4*)qp;
        s16x4 bvn0 = *(const s16x4*)(vp);
        s16x4 bvn1 = *(const s16x4*)(vp + (size_t)16 * NP);
        s16x4 bvn2 = *(const s16x4*)(vp + (size_t)32 * NP);
        s16x4 bvn3 = *(const s16x4*)(vp + (size_t)48 * NP);

        f32x4 z = {0.f, 0.f, 0.f, 0.f};
        f32x4 t0 = mfma16(aq, bq0, z);
        f32x4 t1 = mfma16(aq, bq1, z);

        s16x4 p0 = pack_bf16x4(fexp2(t0[0]), fexp2(t0[1]), fexp2(t0[2]), fexp2(t0[3]));
        s16x4 p1 = pack_bf16x4(fexp2(t1[0]), fexp2(t1[1]), fexp2(t1[2]), fexp2(t1[3]));

        o0[0] = mfma16(p0, bv0, o0[0]);
        o0[1] = mfma16(p0, bv1, o0[1]);
        o0[2] = mfma16(p0, bv2, o0[2]);
        o0[3] = mfma16(p0, bv3, o0[3]);
        o1[0] = mfma16(p1, bv0, o1[0]);
        o1[1] = mfma16(p1, bv1, o1[1]);
        o1[2] = mfma16(p1, bv2, o1[2]);
        o1[3] = mfma16(p1, bv3, o1[3]);

        aq = aqn; bv0 = bvn0; bv1 = bvn1; bv2 = bvn2; bv3 = bvn3;
    }

    // atomic partials into one of 4 O copies (8 contending n-splits each, was 32)
    float* Oc = O4 + (size_t)(nspl & 3) * (NP * 64);
#pragma unroll
    for (int ct = 0; ct < 4; ++ct) {
#pragma unroll
        for (int j = 0; j < 4; ++j) {
            atomicAdd(&Oc[(size_t)(mt0 + 4 * hi + j) * 64 + 16 * ct + lo], o0[ct][j]);
            atomicAdd(&Oc[(size_t)(mt0 + 16 + 4 * hi + j) * 64 + 16 * ct + lo], o1[ct][j]);
        }
    }
}

// per m: XTP[(iy+1)*98 + ix+1][c] = bf16( gamma*(sum_cp O4)/(sum_cp den) + x[c][m] )
__global__ void epi_k(const float* __restrict__ O4, const float* __restrict__ x,
                      const float* __restrict__ gamma, unsigned short* __restrict__ XTP) {
    int m = blockIdx.x * 256 + threadIdx.x;
    if (m >= NP) return;
    int iy = m / WP, ix = m % WP;
    unsigned short* xp = XTP + ((size_t)(iy + 1) * 98 + ix + 1) * 64;
    float den = 0.f;
#pragma unroll
    for (int cp = 0; cp < 4; ++cp) den += O4[(size_t)cp * (NP * 64) + (size_t)m * 64 + 48];
    float rg = gamma[0] / den;
#pragma unroll
    for (int c = 0; c < C; c += 4) {
        f32x4 o4 = O4[(size_t)0 * (NP * 64) + (size_t)m * 64 + c] == O4[(size_t)0 * (NP * 64) + (size_t)m * 64 + c]
                 ? *(const f32x4*)(O4 + (size_t)m * 64 + c) : (f32x4){0.f,0.f,0.f,0.f};
#pragma unroll
        for (int cp = 1; cp < 4; ++cp)
            o4 += *(const f32x4*)(O4 + (size_t)cp * (NP * 64) + (size_t)m * 64 + c);
        ushort4 w;
        w.x = f2bf(rg * o4[0] + x[(size_t)(c + 0) * NP + m]);
        w.y = f2bf(rg * o4[1] + x[(size_t)(c + 1) * NP + m]);
        w.z = f2bf(rg * o4[2] + x[(size_t)(c + 2) * NP + m]);
        w.w = f2bf(rg * o4[3] + x[(size_t)(c + 3) * NP + m]);
        *(ushort4*)(xp + c) = w;
    }
}

// WB[(ky*4+kx)*48+co][ci64] = bf16(dw[ci][co][ky][kx]), ci>=48 -> 0
__global__ void wprep_k(const float* __restrict__ dw, unsigned short* __restrict__ WB) {
    int idx = blockIdx.x * 256 + threadIdx.x;
    if (idx >= 16 * 48 * 64) return;
    int ci = idx & 63;
    int co = (idx >> 6) % 48;
    int kidx = idx / (48 * 64);
    float v = (ci < C) ? dw[((size_t)ci * C + co) * 16 + kidx] : 0.f;
    WB[idx] = f2bf(v);
}

// ConvTranspose2d via MFMA
__global__ __launch_bounds__(128) void convt_mfma_k(const unsigned short* __restrict__ XTP,
                                                    const unsigned short* __restrict__ WB,
                                                    const float* __restrict__ db,
                                                    float* __restrict__ y) {
    const int lane = threadIdx.x & 63;
    const int lo = lane & 15, hi = lane >> 4;
    const int wv = threadIdx.x >> 6;   // 0..1
    const int b = blockIdx.x;          // 96*2*2
    const int oyp = b >> 2;
    const int py = (b >> 1) & 1;
    const int px = b & 1;

    const int sy[2] = {0, py ? 1 : -1};
    const int kyt[2] = {py ? 2 : 1, py ? 0 : 3};
    const int sx[2] = {0, px ? 1 : -1};
    const int kxt[2] = {px ? 2 : 1, px ? 0 : 3};

    s16x8 bw[2][2][2][3];  // [ty][tx][kk][ct]
#pragma unroll
    for (int ty = 0; ty < 2; ++ty)
#pragma unroll
        for (int tx = 0; tx < 2; ++tx) {
            const unsigned short* wp = WB + (size_t)(kyt[ty] * 4 + kxt[tx]) * 48 * 64;
#pragma unroll
            for (int kk = 0; kk < 2; ++kk)
#pragma unroll
                for (int ct = 0; ct < 3; ++ct)
                    bw[ty][tx][kk][ct] = *(const s16x8*)(wp + (size_t)(ct * 16 + lo) * 64 + kk * 32 + 8 * hi);
        }
    float bias[3];
#pragma unroll
    for (int ct = 0; ct < 3; ++ct) bias[ct] = db[ct * 16 + lo];

    const int oy = 2 * oyp + py;
    for (int i = 0; i < 3; ++i) {
        int ox0 = (wv * 3 + i) * 16;
        f32x4 acc[3];
#pragma unroll
        for (int ct = 0; ct < 3; ++ct) acc[ct] = (f32x4){bias[ct], bias[ct], bias[ct], bias[ct]};
#pragma unroll
        for (int ty = 0; ty < 2; ++ty) {
            int R0 = (oyp + sy[ty] + 1) * 98;
#pragma unroll
            for (int tx = 0; tx < 2; ++tx) {
                const unsigned short* ap = XTP + (size_t)(R0 + ox0 + sx[tx] + 1 + lo) * 64 + 8 * hi;
#pragma unroll
                for (int kk = 0; kk < 2; ++kk) {
                    s16x8 a = *(const s16x8*)(ap + kk * 32);
                    acc[0] = mfma32(a, bw[ty][tx][kk][0], acc[0]);
                    acc[1] = mfma32(a, bw[ty][tx][kk][1], acc[1]);
                    acc[2] = mfma32(a, bw[ty][tx][kk][2], acc[2]);
                }
            }
        }
#pragma unroll
        for (int ct = 0; ct < 3; ++ct)
#pragma unroll
            for (int j = 0; j < 4; ++j)
                y[(size_t)(ct * 16 + lo) * (HH * WW) + oy * WW + 2 * (ox0 + 4 * hi + j) + px] = acc[ct][j];
    }
}

extern "C" void kernel_launch(void* const* d_in, const int* in_sizes, int n_in,
                              void* d_out, int out_size, void* d_ws, size_t ws_size,
                              hipStream_t stream) {
    const float* in    = (const float*)d_in[0];
    const float* qw    = (const float*)d_in[1];
    const float* qb    = (const float*)d_in[2];
    const float* kw    = (const float*)d_in[3];
    const float* kb    = (const float*)d_in[4];
    const float* vw    = (const float*)d_in[5];
    const float* vb    = (const float*)d_in[6];
    const float* gamma = (const float*)d_in[7];
    const float* dw    = (const float*)d_in[8];
    const float* db    = (const float*)d_in[9];
    float* out = (float*)d_out;

    float* ws = (float*)d_ws;
    float* x  = ws + OFF_X;
    unsigned short* QB  = (unsigned short*)(ws + OFF_QB);
    unsigned short* KB  = (unsigned short*)(ws + OFF_KB);
    unsigned short* VB  = (unsigned short*)(ws + OFF_VB);
    unsigned short* XTP = (unsigned short*)(ws + OFF_XTP);
    unsigned short* WB  = (unsigned short*)(ws + OFF_WB);
    float* O4 = ws + OFF_O4;

    pool_k<<<(C * NP + 255) / 256, 256, 0, stream>>>(in, x);
    qkvprep_k<<<(5 * NP) / 256, 256, 0, stream>>>(x, qw, qb, kw, kb, vw, vb, QB, KB, VB);
    hipMemsetAsync(XTP, 0, (size_t)98 * 98 * 64 * sizeof(unsigned short), stream);
    hipMemsetAsync(O4, 0, (size_t)4 * NP * 64 * sizeof(float), stream);
    wprep_k<<<(16 * 48 * 64) / 256, 256, 0, stream>>>(dw, WB);
    attn_k<<<MBLKS * NSPL, 256, 0, stream>>>(QB, KB, VB, O4);
    epi_k<<<(NP + 255) / 256, 256, 0, stream>>>(O4, x, gamma, XTP);
    convt_mfma_k<<<96 * 2 * 2, 128, 0, stream>>>(XTP, WB, db, out);
}

// Round 9
// 140.625 us; speedup vs baseline: 1.1797x; 1.1797x over previous
//
#include <hip/hip_runtime.h>
#include <hip/hip_bf16.h>

#define C 48
#define HH 192
#define WW 192
#define HP 96
#define WP 96
#define NP 9216   // 96*96

// ws layout (float offsets), compact. total 5,861,504 fl = 23,446,016 B (proven fits)
#define OFF_QB    0         // QB: [9216][16] bf16
#define OFF_KB    36864     // KB: [9216][16] bf16 (pre-scaled by log2e)
#define OFF_VB    73728     // VB: [64][9216] bf16 (row 48=1.0, 49..63=0)
#define OFF_PART  368640    // PART: [288][16][2048] bf16 (fragment-order partials)
#define OFF_XT    5087232   // xT: [9216][48] f32
#define OFF_XTP   5529600   // XTP: [98*98][64] bf16, halo+ci-pad zeros
#define OFF_WB    5836928   // WB: [16][48][64] bf16
#define WS_NEED_BYTES ((size_t)5861504 * 4)

typedef __attribute__((ext_vector_type(4))) short s16x4;
typedef __attribute__((ext_vector_type(8))) short s16x8;
typedef __attribute__((ext_vector_type(4))) float f32x4;

#if __has_builtin(__builtin_amdgcn_mfma_f32_16x16x16bf16_1k)
static __device__ inline f32x4 mfma16(s16x4 a, s16x4 b, f32x4 c) {
    return __builtin_amdgcn_mfma_f32_16x16x16bf16_1k(a, b, c, 0, 0, 0);
}
#else
static __device__ inline f32x4 mfma16(s16x4 a, s16x4 b, f32x4 c) {
    asm volatile("v_mfma_f32_16x16x16_bf16 %0, %1, %2, %0" : "+v"(c) : "v"(a), "v"(b));
    return c;
}
#endif

static __device__ inline f32x4 mfma32(s16x8 a, s16x8 b, f32x4 c) {
    return __builtin_amdgcn_mfma_f32_16x16x32_bf16(a, b, c, 0, 0, 0);
}

// raw v_exp_f32: computes 2^x (scores pre-scaled by log2e) — R4/R8-proven codegen
static __device__ inline float fexp2(float x) {
    float r;
    asm("v_exp_f32 %0, %1" : "=v"(r) : "v"(x));
    return r;
}

static __device__ inline unsigned short f2bf(float f) {
    union { float f; unsigned u; } v; v.f = f;
    unsigned r = v.u + 0x7fff + ((v.u >> 16) & 1);
    return (unsigned short)(r >> 16);
}

static __device__ inline float bf2f(unsigned short u) {
    union { unsigned u; float f; } v; v.u = ((unsigned)u) << 16; return v.f;
}

static __device__ inline s16x4 pack_bf16x4(float a, float b, float c, float d) {
    __hip_bfloat162 h0 = __float22bfloat162_rn(make_float2(a, b));
    __hip_bfloat162 h1 = __float22bfloat162_rn(make_float2(c, d));
    union { unsigned u[2]; s16x4 v; } pu;
    pu.u[0] = *reinterpret_cast<unsigned*>(&h0);
    pu.u[1] = *reinterpret_cast<unsigned*>(&h1);
    return pu.v;
}

// pooled residual, transposed: xT[p][c]
__global__ void pool_k(const float* __restrict__ in, float* __restrict__ xT) {
    int idx = blockIdx.x * 256 + threadIdx.x;
    if (idx >= C * NP) return;
    int c = idx / NP, r = idx % NP;
    int y = r / WP, xx = r % WP;
    const float* p = in + (size_t)c * HH * WW + (2 * y) * WW + 2 * xx;
    xT[(size_t)r * 48 + c] = 0.25f * (p[0] + p[1] + p[WW] + p[WW + 1]);
}

__global__ void qkvprep_k(const float* __restrict__ xT,
                          const float* __restrict__ qw, const float* __restrict__ qb,
                          const float* __restrict__ kw, const float* __restrict__ kb,
                          const float* __restrict__ vw, const float* __restrict__ vb,
                          unsigned short* __restrict__ QB, unsigned short* __restrict__ KB,
                          unsigned short* __restrict__ VB) {
    int tid = blockIdx.x * 256 + threadIdx.x;   // 5*9216 threads
    int p = tid % NP;
    int g = tid / NP;
    float f[C];
#pragma unroll
    for (int c4 = 0; c4 < C; c4 += 4) {
        f32x4 v = *(const f32x4*)(xT + (size_t)p * 48 + c4);
        f[c4] = v[0]; f[c4 + 1] = v[1]; f[c4 + 2] = v[2]; f[c4 + 3] = v[3];
    }
    if (g == 0) {
#pragma unroll
        for (int o = 0; o < 16; ++o) {
            float a = qb[o];
#pragma unroll
            for (int c = 0; c < C; ++c) a += qw[o * C + c] * f[c];
            QB[p * 16 + o] = f2bf(a);
        }
    } else if (g == 1) {
        const float L2E = 1.4426950408889634f;
#pragma unroll
        for (int o = 0; o < 16; ++o) {
            float a = kb[o];
#pragma unroll
            for (int c = 0; c < C; ++c) a += kw[o * C + c] * f[c];
            KB[p * 16 + o] = f2bf(a * L2E);
        }
        VB[(size_t)48 * NP + p] = 0x3F80;  // bf16(1.0) -> den row
#pragma unroll
        for (int r = 49; r < 64; ++r) VB[(size_t)r * NP + p] = 0;
    } else {
        int c0 = (g - 2) * 16;
#pragma unroll
        for (int oo = 0; oo < 16; ++oo) {
            int o = c0 + oo;
            float a = vb[o];
#pragma unroll
            for (int c = 0; c < C; ++c) a += vw[o * C + c] * f[c];
            VB[(size_t)o * NP + p] = f2bf(a);
        }
    }
}

#define MBLKS 72
#define NSPL  16
#define NSTEP 36   // (NP/NSPL)/16

// R8-proven inner loop, verbatim (prefetch, raw-asm exp, no LDS)
static __device__ __forceinline__ void attn_core(const unsigned short* __restrict__ QB,
                                                 const unsigned short* __restrict__ VB,
                                                 s16x4 bq0, s16x4 bq1, int n0, int lo, int hi,
                                                 f32x4 o0[4], f32x4 o1[4]) {
    const unsigned short* qp = QB + (size_t)(n0 + lo) * 16 + 4 * hi;
    const unsigned short* vp = VB + (size_t)lo * NP + n0 + 4 * hi;

    s16x4 aq  = *(const s16x4*)qp;
    s16x4 bv0 = *(const s16x4*)(vp);
    s16x4 bv1 = *(const s16x4*)(vp + (size_t)16 * NP);
    s16x4 bv2 = *(const s16x4*)(vp + (size_t)32 * NP);
    s16x4 bv3 = *(const s16x4*)(vp + (size_t)48 * NP);

    for (int s = 0; s < NSTEP; ++s) {
        qp += 16 * 16;
        vp += 16;
        // prefetch next tile (tail over-read stays inside d_ws; values unused)
        s16x4 aqn  = *(const s16x4*)qp;
        s16x4 bvn0 = *(const s16x4*)(vp);
        s16x4 bvn1 = *(const s16x4*)(vp + (size_t)16 * NP);
        s16x4 bvn2 = *(const s16x4*)(vp + (size_t)32 * NP);
        s16x4 bvn3 = *(const s16x4*)(vp + (size_t)48 * NP);

        f32x4 z = {0.f, 0.f, 0.f, 0.f};
        f32x4 t0 = mfma16(aq, bq0, z);
        f32x4 t1 = mfma16(aq, bq1, z);

        s16x4 p0 = pack_bf16x4(fexp2(t0[0]), fexp2(t0[1]), fexp2(t0[2]), fexp2(t0[3]));
        s16x4 p1 = pack_bf16x4(fexp2(t1[0]), fexp2(t1[1]), fexp2(t1[2]), fexp2(t1[3]));

        o0[0] = mfma16(p0, bv0, o0[0]);
        o0[1] = mfma16(p0, bv1, o0[1]);
        o0[2] = mfma16(p0, bv2, o0[2]);
        o0[3] = mfma16(p0, bv3, o0[3]);
        o1[0] = mfma16(p1, bv0, o1[0]);
        o1[1] = mfma16(p1, bv1, o1[1]);
        o1[2] = mfma16(p1, bv2, o1[2]);
        o1[3] = mfma16(p1, bv3, o1[3]);

        aq = aqn; bv0 = bvn0; bv1 = bvn1; bv2 = bvn2; bv3 = bvn3;
    }
}

// Main: atomic-free. Each wave stores its 32x64 partial as bf16 in fragment order:
// chunk[q*256 + lane*4 + j], q = h*4+ct. Plain coalesced 8B stores, no LDS.
__global__ __launch_bounds__(256) void attn_k(const unsigned short* __restrict__ QB,
                                              const unsigned short* __restrict__ KB,
                                              const unsigned short* __restrict__ VB,
                                              unsigned short* __restrict__ PART) {
    const int lane = threadIdx.x & 63;
    const int lo = lane & 15, hi = lane >> 4;
    const int wv = threadIdx.x >> 6;
    const int mblk = blockIdx.x % MBLKS;
    const int nspl = blockIdx.x / MBLKS;
    const int mt0 = mblk * 128 + wv * 32;

    const s16x4 bq0 = *(const s16x4*)(KB + (size_t)(mt0 + lo) * 16 + 4 * hi);
    const s16x4 bq1 = *(const s16x4*)(KB + (size_t)(mt0 + 16 + lo) * 16 + 4 * hi);

    f32x4 o0[4], o1[4];
#pragma unroll
    for (int i = 0; i < 4; ++i) {
        o0[i] = (f32x4){0.f, 0.f, 0.f, 0.f};
        o1[i] = (f32x4){0.f, 0.f, 0.f, 0.f};
    }
    attn_core(QB, VB, bq0, bq1, nspl * (NP / NSPL), lo, hi, o0, o1);

    unsigned short* cp = PART + ((size_t)(mblk * 4 + wv) * NSPL + nspl) * 2048;
#pragma unroll
    for (int q = 0; q < 8; ++q) {
        const f32x4& o = (q >> 2) ? o1[q & 3] : o0[q & 3];
        s16x4 pk = pack_bf16x4(o[0], o[1], o[2], o[3]);
        *(s16x4*)(cp + q * 256 + lane * 4) = pk;
    }
}

// Reduce 16 chunks + epilogue. One block per 32-m tile. No MFMA, tiny LDS for den only.
__global__ __launch_bounds__(256) void reduce_epi_k(const unsigned short* __restrict__ PART,
                                                    const float* __restrict__ xT,
                                                    const float* __restrict__ gamma,
                                                    unsigned short* __restrict__ XTP) {
    __shared__ float sden[32];
    const int T = blockIdx.x;          // 288 tiles
    const int mt0 = (T >> 2) * 128 + (T & 3) * 32;
    const unsigned short* base = PART + (size_t)T * NSPL * 2048;
    const int t = threadIdx.x;

    if (t < 8) {   // den: c=48 -> ct=3, lo=0; groups (h,hi)
        int h = t >> 2, hi = t & 3;
        int idx = (h * 4 + 3) * 256 + (hi * 16) * 4;
        float a0 = 0.f, a1 = 0.f, a2 = 0.f, a3 = 0.f;
        for (int ns = 0; ns < NSPL; ++ns) {
            s16x4 v = *(const s16x4*)(base + ns * 2048 + idx);
            a0 += bf2f((unsigned short)v[0]);
            a1 += bf2f((unsigned short)v[1]);
            a2 += bf2f((unsigned short)v[2]);
            a3 += bf2f((unsigned short)v[3]);
        }
        sden[h * 16 + hi * 4 + 0] = a0;
        sden[h * 16 + hi * 4 + 1] = a1;
        sden[h * 16 + hi * 4 + 2] = a2;
        sden[h * 16 + hi * 4 + 3] = a3;
    }
    __syncthreads();

    float gam = gamma[0];
#pragma unroll
    for (int g = t; g < 512; g += 256) {
        int q = g >> 6, lane = g & 63;
        int h = q >> 2, ct = q & 3;
        int hi = lane >> 4, lo = lane & 15;
        int c = ct * 16 + lo;
        int idx = q * 256 + lane * 4;
        float a0 = 0.f, a1 = 0.f, a2 = 0.f, a3 = 0.f;
        for (int ns = 0; ns < NSPL; ++ns) {
            s16x4 v = *(const s16x4*)(base + ns * 2048 + idx);
            a0 += bf2f((unsigned short)v[0]);
            a1 += bf2f((unsigned short)v[1]);
            a2 += bf2f((unsigned short)v[2]);
            a3 += bf2f((unsigned short)v[3]);
        }
        if (c < 48) {
            float av[4] = {a0, a1, a2, a3};
#pragma unroll
            for (int j = 0; j < 4; ++j) {
                int ml = h * 16 + hi * 4 + j;
                int m = mt0 + ml;
                float val = gam * av[j] / sden[ml] + xT[(size_t)m * 48 + c];
                int iy = m / WP, ix = m % WP;
                XTP[((size_t)(iy + 1) * 98 + ix + 1) * 64 + c] = f2bf(val);
            }
        }
    }
}

// ---------- fallback path (small ws): R8-proven atomics (O4 overlays PART) ----------
__global__ __launch_bounds__(256) void attn_atomic_k(const unsigned short* __restrict__ QB,
                                                     const unsigned short* __restrict__ KB,
                                                     const unsigned short* __restrict__ VB,
                                                     float* __restrict__ O4) {
    const int lane = threadIdx.x & 63;
    const int lo = lane & 15, hi = lane >> 4;
    const int wv = threadIdx.x >> 6;
    const int mblk = blockIdx.x % MBLKS;
    const int nspl = blockIdx.x / MBLKS;
    const int mt0 = mblk * 128 + wv * 32;

    const s16x4 bq0 = *(const s16x4*)(KB + (size_t)(mt0 + lo) * 16 + 4 * hi);
    const s16x4 bq1 = *(const s16x4*)(KB + (size_t)(mt0 + 16 + lo) * 16 + 4 * hi);

    f32x4 o0[4], o1[4];
#pragma unroll
    for (int i = 0; i < 4; ++i) {
        o0[i] = (f32x4){0.f, 0.f, 0.f, 0.f};
        o1[i] = (f32x4){0.f, 0.f, 0.f, 0.f};
    }
    attn_core(QB, VB, bq0, bq1, nspl * (NP / NSPL), lo, hi, o0, o1);

    float* Oc = O4 + (size_t)(nspl & 3) * (NP * 64);
#pragma unroll
    for (int ct = 0; ct < 4; ++ct)
#pragma unroll
        for (int j = 0; j < 4; ++j) {
            atomicAdd(&Oc[(size_t)(mt0 + 4 * hi + j) * 64 + 16 * ct + lo], o0[ct][j]);
            atomicAdd(&Oc[(size_t)(mt0 + 16 + 4 * hi + j) * 64 + 16 * ct + lo], o1[ct][j]);
        }
}

__global__ void epi_atomic_k(const float* __restrict__ O4, const float* __restrict__ xT,
                             const float* __restrict__ gamma, unsigned short* __restrict__ XTP) {
    int m = blockIdx.x * 256 + threadIdx.x;
    if (m >= NP) return;
    int iy = m / WP, ix = m % WP;
    unsigned short* xp = XTP + ((size_t)(iy + 1) * 98 + ix + 1) * 64;
    float den = 0.f;
#pragma unroll
    for (int cp = 0; cp < 4; ++cp) den += O4[(size_t)cp * (NP * 64) + (size_t)m * 64 + 48];
    float rg = gamma[0] / den;
#pragma unroll
    for (int c = 0; c < C; ++c) {
        float o = 0.f;
#pragma unroll
        for (int cp = 0; cp < 4; ++cp) o += O4[(size_t)cp * (NP * 64) + (size_t)m * 64 + c];
        xp[c] = f2bf(rg * o + xT[(size_t)m * 48 + c]);
    }
}

// WB[(ky*4+kx)*48+co][ci64] = bf16(dw[ci][co][ky][kx]), ci>=48 -> 0
__global__ void wprep_k(const float* __restrict__ dw, unsigned short* __restrict__ WB) {
    int idx = blockIdx.x * 256 + threadIdx.x;
    if (idx >= 16 * 48 * 64) return;
    int ci = idx & 63;
    int co = (idx >> 6) % 48;
    int kidx = idx / (48 * 64);
    float v = (ci < C) ? dw[((size_t)ci * C + co) * 16 + kidx] : 0.f;
    WB[idx] = f2bf(v);
}

// ConvTranspose2d via MFMA
__global__ __launch_bounds__(128) void convt_mfma_k(const unsigned short* __restrict__ XTP,
                                                    const unsigned short* __restrict__ WB,
                                                    const float* __restrict__ db,
                                                    float* __restrict__ y) {
    const int lane = threadIdx.x & 63;
    const int lo = lane & 15, hi = lane >> 4;
    const int wv = threadIdx.x >> 6;   // 0..1
    const int b = blockIdx.x;          // 96*2*2
    const int oyp = b >> 2;
    const int py = (b >> 1) & 1;
    const int px = b & 1;

    const int sy[2] = {0, py ? 1 : -1};
    const int kyt[2] = {py ? 2 : 1, py ? 0 : 3};
    const int sx[2] = {0, px ? 1 : -1};
    const int kxt[2] = {px ? 2 : 1, px ? 0 : 3};

    s16x8 bw[2][2][2][3];  // [ty][tx][kk][ct]
#pragma unroll
    for (int ty = 0; ty < 2; ++ty)
#pragma unroll
        for (int tx = 0; tx < 2; ++tx) {
            const unsigned short* wp = WB + (size_t)(kyt[ty] * 4 + kxt[tx]) * 48 * 64;
#pragma unroll
            for (int kk = 0; kk < 2; ++kk)
#pragma unroll
                for (int ct = 0; ct < 3; ++ct)
                    bw[ty][tx][kk][ct] = *(const s16x8*)(wp + (size_t)(ct * 16 + lo) * 64 + kk * 32 + 8 * hi);
        }
    float bias[3];
#pragma unroll
    for (int ct = 0; ct < 3; ++ct) bias[ct] = db[ct * 16 + lo];

    const int oy = 2 * oyp + py;
    for (int i = 0; i < 3; ++i) {
        int ox0 = (wv * 3 + i) * 16;
        f32x4 acc[3];
#pragma unroll
        for (int ct = 0; ct < 3; ++ct) acc[ct] = (f32x4){bias[ct], bias[ct], bias[ct], bias[ct]};
#pragma unroll
        for (int ty = 0; ty < 2; ++ty) {
            int R0 = (oyp + sy[ty] + 1) * 98;
#pragma unroll
            for (int tx = 0; tx < 2; ++tx) {
                const unsigned short* ap = XTP + (size_t)(R0 + ox0 + sx[tx] + 1 + lo) * 64 + 8 * hi;
#pragma unroll
                for (int kk = 0; kk < 2; ++kk) {
                    s16x8 a = *(const s16x8*)(ap + kk * 32);
                    acc[0] = mfma32(a, bw[ty][tx][kk][0], acc[0]);
                    acc[1] = mfma32(a, bw[ty][tx][kk][1], acc[1]);
                    acc[2] = mfma32(a, bw[ty][tx][kk][2], acc[2]);
                }
            }
        }
#pragma unroll
        for (int ct = 0; ct < 3; ++ct)
#pragma unroll
            for (int j = 0; j < 4; ++j)
                y[(size_t)(ct * 16 + lo) * (HH * WW) + oy * WW + 2 * (ox0 + 4 * hi + j) + px] = acc[ct][j];
    }
}

extern "C" void kernel_launch(void* const* d_in, const int* in_sizes, int n_in,
                              void* d_out, int out_size, void* d_ws, size_t ws_size,
                              hipStream_t stream) {
    const float* in    = (const float*)d_in[0];
    const float* qw    = (const float*)d_in[1];
    const float* qb    = (const float*)d_in[2];
    const float* kw    = (const float*)d_in[3];
    const float* kb    = (const float*)d_in[4];
    const float* vw    = (const float*)d_in[5];
    const float* vb    = (const float*)d_in[6];
    const float* gamma = (const float*)d_in[7];
    const float* dw    = (const float*)d_in[8];
    const float* db    = (const float*)d_in[9];
    float* out = (float*)d_out;

    float* ws = (float*)d_ws;
    unsigned short* QB   = (unsigned short*)(ws + OFF_QB);
    unsigned short* KB   = (unsigned short*)(ws + OFF_KB);
    unsigned short* VB   = (unsigned short*)(ws + OFF_VB);
    unsigned short* PART = (unsigned short*)(ws + OFF_PART);
    float*          xT   = ws + OFF_XT;
    unsigned short* XTP  = (unsigned short*)(ws + OFF_XTP);
    unsigned short* WB   = (unsigned short*)(ws + OFF_WB);

    pool_k<<<(C * NP + 255) / 256, 256, 0, stream>>>(in, xT);
    qkvprep_k<<<(5 * NP) / 256, 256, 0, stream>>>(xT, qw, qb, kw, kb, vw, vb, QB, KB, VB);
    hipMemsetAsync(XTP, 0, (size_t)98 * 98 * 64 * sizeof(unsigned short), stream);
    wprep_k<<<(16 * 48 * 64) / 256, 256, 0, stream>>>(dw, WB);

    if (ws_size >= WS_NEED_BYTES) {
        attn_k<<<MBLKS * NSPL, 256, 0, stream>>>(QB, KB, VB, PART);
        reduce_epi_k<<<288, 256, 0, stream>>>(PART, xT, gamma, XTP);
    } else {
        float* O4 = (float*)PART;   // overlays PART region (9.4 MB < 18.9 MB)
        hipMemsetAsync(O4, 0, (size_t)4 * NP * 64 * sizeof(float), stream);
        attn_atomic_k<<<MBLKS * NSPL, 256, 0, stream>>>(QB, KB, VB, O4);
        epi_atomic_k<<<(NP + 255) / 256, 256, 0, stream>>>(O4, xT, gamma, XTP);
    }
    convt_mfma_k<<<96 * 2 * 2, 128, 0, stream>>>(XTP, WB, db, out);
}

// Round 10
// 85.980 us; speedup vs baseline: 1.9295x; 1.6355x over previous
//
#include <hip/hip_runtime.h>
#include <hip/hip_bf16.h>

#define C 48
#define HH 192
#define WW 192
#define HP 96
#define WP 96
#define NP 9216   // 96*96

// ws layout (float offsets), compact. total 5,861,504 fl = 23,446,016 B (proven fits)
#define OFF_QB    0         // QB: [9216][16] bf16
#define OFF_KB    36864     // KB: [9216][16] bf16 (pre-scaled by log2e)
#define OFF_VT2   73728     // VT2: [576][64][16] bf16 (row 48=1.0, 49..63=0)
#define OFF_PART  368640    // PART: [288][16][2048] bf16 (fragment-order partials)
#define OFF_XT    5087232   // xT: [9216][48] f32
#define OFF_XTP   5529600   // XTP: [98*98][64] bf16, halo+ci-pad zeros
#define OFF_WB    5836928   // WB: [16][48][64] bf16
#define WS_NEED_BYTES ((size_t)5861504 * 4)

typedef __attribute__((ext_vector_type(4))) short s16x4;
typedef __attribute__((ext_vector_type(8))) short s16x8;
typedef __attribute__((ext_vector_type(4))) float f32x4;

#if __has_builtin(__builtin_amdgcn_mfma_f32_16x16x16bf16_1k)
static __device__ inline f32x4 mfma16(s16x4 a, s16x4 b, f32x4 c) {
    return __builtin_amdgcn_mfma_f32_16x16x16bf16_1k(a, b, c, 0, 0, 0);
}
#else
static __device__ inline f32x4 mfma16(s16x4 a, s16x4 b, f32x4 c) {
    asm volatile("v_mfma_f32_16x16x16_bf16 %0, %1, %2, %0" : "+v"(c) : "v"(a), "v"(b));
    return c;
}
#endif

static __device__ inline f32x4 mfma32(s16x8 a, s16x8 b, f32x4 c) {
    return __builtin_amdgcn_mfma_f32_16x16x32_bf16(a, b, c, 0, 0, 0);
}

// raw v_exp_f32: computes 2^x (scores pre-scaled by log2e) — R4/R8/R9-proven codegen
static __device__ inline float fexp2(float x) {
    float r;
    asm("v_exp_f32 %0, %1" : "=v"(r) : "v"(x));
    return r;
}

static __device__ inline unsigned short f2bf(float f) {
    union { float f; unsigned u; } v; v.f = f;
    unsigned r = v.u + 0x7fff + ((v.u >> 16) & 1);
    return (unsigned short)(r >> 16);
}

static __device__ inline float bf2f(unsigned short u) {
    union { unsigned u; float f; } v; v.u = ((unsigned)u) << 16; return v.f;
}

static __device__ inline s16x4 pack_bf16x4(float a, float b, float c, float d) {
    __hip_bfloat162 h0 = __float22bfloat162_rn(make_float2(a, b));
    __hip_bfloat162 h1 = __float22bfloat162_rn(make_float2(c, d));
    union { unsigned u[2]; s16x4 v; } pu;
    pu.u[0] = *reinterpret_cast<unsigned*>(&h0);
    pu.u[1] = *reinterpret_cast<unsigned*>(&h1);
    return pu.v;
}

// pooled residual, transposed: xT[p][c]
__global__ void pool_k(const float* __restrict__ in, float* __restrict__ xT) {
    int idx = blockIdx.x * 256 + threadIdx.x;
    if (idx >= C * NP) return;
    int c = idx / NP, r = idx % NP;
    int y = r / WP, xx = r % WP;
    const float* p = in + (size_t)c * HH * WW + (2 * y) * WW + 2 * xx;
    xT[(size_t)r * 48 + c] = 0.25f * (p[0] + p[1] + p[WW] + p[WW + 1]);
}

__global__ void qkvprep_k(const float* __restrict__ xT,
                          const float* __restrict__ qw, const float* __restrict__ qb,
                          const float* __restrict__ kw, const float* __restrict__ kb,
                          const float* __restrict__ vw, const float* __restrict__ vb,
                          unsigned short* __restrict__ QB, unsigned short* __restrict__ KB,
                          unsigned short* __restrict__ VT2) {
    int tid = blockIdx.x * 256 + threadIdx.x;   // 5*9216 threads
    int p = tid % NP;
    int g = tid / NP;
    float f[C];
#pragma unroll
    for (int c4 = 0; c4 < C; c4 += 4) {
        f32x4 v = *(const f32x4*)(xT + (size_t)p * 48 + c4);
        f[c4] = v[0]; f[c4 + 1] = v[1]; f[c4 + 2] = v[2]; f[c4 + 3] = v[3];
    }
    int nt = p >> 4, nn = p & 15;
    if (g == 0) {
#pragma unroll
        for (int o = 0; o < 16; ++o) {
            float a = qb[o];
#pragma unroll
            for (int c = 0; c < C; ++c) a += qw[o * C + c] * f[c];
            QB[p * 16 + o] = f2bf(a);
        }
    } else if (g == 1) {
        const float L2E = 1.4426950408889634f;
#pragma unroll
        for (int o = 0; o < 16; ++o) {
            float a = kb[o];
#pragma unroll
            for (int c = 0; c < C; ++c) a += kw[o * C + c] * f[c];
            KB[p * 16 + o] = f2bf(a * L2E);
        }
        VT2[(size_t)nt * 1024 + 48 * 16 + nn] = 0x3F80;  // row 48 = ones (den)
#pragma unroll
        for (int r = 49; r < 64; ++r) VT2[(size_t)nt * 1024 + r * 16 + nn] = 0;
    } else {
        int c0 = (g - 2) * 16;
#pragma unroll
        for (int oo = 0; oo < 16; ++oo) {
            int o = c0 + oo;
            float a = vb[o];
#pragma unroll
            for (int c = 0; c < C; ++c) a += vw[o * C + c] * f[c];
            VT2[(size_t)nt * 1024 + o * 16 + nn] = f2bf(a);
        }
    }
}

#define MBLKS 72
#define NSPL  16
#define NSTEP 36   // (NP/NSPL)/16

// R9-proven inner loop; ONLY vp addressing changed to the n-tiled VT2 layout
// (each bv load is now one contiguous 512B wave transaction instead of 16
//  scattered 32B segments at 18KB lane-stride).
static __device__ __forceinline__ void attn_core(const unsigned short* __restrict__ QB,
                                                 const unsigned short* __restrict__ VT2,
                                                 s16x4 bq0, s16x4 bq1, int n0, int lo, int hi,
                                                 f32x4 o0[4], f32x4 o1[4]) {
    const unsigned short* qp = QB + (size_t)(n0 + lo) * 16 + 4 * hi;
    const unsigned short* vp = VT2 + (size_t)(n0 >> 4) * 1024 + lo * 16 + 4 * hi;

    s16x4 aq  = *(const s16x4*)qp;
    s16x4 bv0 = *(const s16x4*)(vp);
    s16x4 bv1 = *(const s16x4*)(vp + 256);
    s16x4 bv2 = *(const s16x4*)(vp + 512);
    s16x4 bv3 = *(const s16x4*)(vp + 768);

    for (int s = 0; s < NSTEP; ++s) {
        qp += 16 * 16;
        vp += 1024;
        // prefetch next tile (tail over-read stays inside d_ws; values unused)
        s16x4 aqn  = *(const s16x4*)qp;
        s16x4 bvn0 = *(const s16x4*)(vp);
        s16x4 bvn1 = *(const s16x4*)(vp + 256);
        s16x4 bvn2 = *(const s16x4*)(vp + 512);
        s16x4 bvn3 = *(const s16x4*)(vp + 768);

        f32x4 z = {0.f, 0.f, 0.f, 0.f};
        f32x4 t0 = mfma16(aq, bq0, z);
        f32x4 t1 = mfma16(aq, bq1, z);

        s16x4 p0 = pack_bf16x4(fexp2(t0[0]), fexp2(t0[1]), fexp2(t0[2]), fexp2(t0[3]));
        s16x4 p1 = pack_bf16x4(fexp2(t1[0]), fexp2(t1[1]), fexp2(t1[2]), fexp2(t1[3]));

        o0[0] = mfma16(p0, bv0, o0[0]);
        o0[1] = mfma16(p0, bv1, o0[1]);
        o0[2] = mfma16(p0, bv2, o0[2]);
        o0[3] = mfma16(p0, bv3, o0[3]);
        o1[0] = mfma16(p1, bv0, o1[0]);
        o1[1] = mfma16(p1, bv1, o1[1]);
        o1[2] = mfma16(p1, bv2, o1[2]);
        o1[3] = mfma16(p1, bv3, o1[3]);

        aq = aqn; bv0 = bvn0; bv1 = bvn1; bv2 = bvn2; bv3 = bvn3;
    }
}

// Atomic-free: each wave stores its 32x64 partial as bf16 in fragment order.
__global__ __launch_bounds__(256) void attn_k(const unsigned short* __restrict__ QB,
                                              const unsigned short* __restrict__ KB,
                                              const unsigned short* __restrict__ VT2,
                                              unsigned short* __restrict__ PART) {
    const int lane = threadIdx.x & 63;
    const int lo = lane & 15, hi = lane >> 4;
    const int wv = threadIdx.x >> 6;
    const int mblk = blockIdx.x % MBLKS;
    const int nspl = blockIdx.x / MBLKS;
    const int mt0 = mblk * 128 + wv * 32;

    const s16x4 bq0 = *(const s16x4*)(KB + (size_t)(mt0 + lo) * 16 + 4 * hi);
    const s16x4 bq1 = *(const s16x4*)(KB + (size_t)(mt0 + 16 + lo) * 16 + 4 * hi);

    f32x4 o0[4], o1[4];
#pragma unroll
    for (int i = 0; i < 4; ++i) {
        o0[i] = (f32x4){0.f, 0.f, 0.f, 0.f};
        o1[i] = (f32x4){0.f, 0.f, 0.f, 0.f};
    }
    attn_core(QB, VT2, bq0, bq1, nspl * (NP / NSPL), lo, hi, o0, o1);

    unsigned short* cp = PART + ((size_t)(mblk * 4 + wv) * NSPL + nspl) * 2048;
#pragma unroll
    for (int q = 0; q < 8; ++q) {
        const f32x4& o = (q >> 2) ? o1[q & 3] : o0[q & 3];
        s16x4 pk = pack_bf16x4(o[0], o[1], o[2], o[3]);
        *(s16x4*)(cp + q * 256 + lane * 4) = pk;
    }
}

// Reduce 16 chunks + epilogue. One block per 32-m tile.
__global__ __launch_bounds__(256) void reduce_epi_k(const unsigned short* __restrict__ PART,
                                                    const float* __restrict__ xT,
                                                    const float* __restrict__ gamma,
                                                    unsigned short* __restrict__ XTP) {
    __shared__ float sden[32];
    const int T = blockIdx.x;          // 288 tiles
    const int mt0 = (T >> 2) * 128 + (T & 3) * 32;
    const unsigned short* base = PART + (size_t)T * NSPL * 2048;
    const int t = threadIdx.x;

    if (t < 8) {   // den: c=48 -> ct=3, lo=0; groups (h,hi)
        int h = t >> 2, hi = t & 3;
        int idx = (h * 4 + 3) * 256 + (hi * 16) * 4;
        float a0 = 0.f, a1 = 0.f, a2 = 0.f, a3 = 0.f;
        for (int ns = 0; ns < NSPL; ++ns) {
            s16x4 v = *(const s16x4*)(base + ns * 2048 + idx);
            a0 += bf2f((unsigned short)v[0]);
            a1 += bf2f((unsigned short)v[1]);
            a2 += bf2f((unsigned short)v[2]);
            a3 += bf2f((unsigned short)v[3]);
        }
        sden[h * 16 + hi * 4 + 0] = a0;
        sden[h * 16 + hi * 4 + 1] = a1;
        sden[h * 16 + hi * 4 + 2] = a2;
        sden[h * 16 + hi * 4 + 3] = a3;
    }
    __syncthreads();

    float gam = gamma[0];
#pragma unroll
    for (int g = t; g < 512; g += 256) {
        int q = g >> 6, lane = g & 63;
        int h = q >> 2, ct = q & 3;
        int hi = lane >> 4, lo = lane & 15;
        int c = ct * 16 + lo;
        int idx = q * 256 + lane * 4;
        float a0 = 0.f, a1 = 0.f, a2 = 0.f, a3 = 0.f;
        for (int ns = 0; ns < NSPL; ++ns) {
            s16x4 v = *(const s16x4*)(base + ns * 2048 + idx);
            a0 += bf2f((unsigned short)v[0]);
            a1 += bf2f((unsigned short)v[1]);
            a2 += bf2f((unsigned short)v[2]);
            a3 += bf2f((unsigned short)v[3]);
        }
        if (c < 48) {
            float av[4] = {a0, a1, a2, a3};
#pragma unroll
            for (int j = 0; j < 4; ++j) {
                int ml = h * 16 + hi * 4 + j;
                int m = mt0 + ml;
                float val = gam * av[j] / sden[ml] + xT[(size_t)m * 48 + c];
                int iy = m / WP, ix = m % WP;
                XTP[((size_t)(iy + 1) * 98 + ix + 1) * 64 + c] = f2bf(val);
            }
        }
    }
}

// ---------- fallback path (small ws): atomics into O4 (overlays PART) ----------
__global__ __launch_bounds__(256) void attn_atomic_k(const unsigned short* __restrict__ QB,
                                                     const unsigned short* __restrict__ KB,
                                                     const unsigned short* __restrict__ VT2,
                                                     float* __restrict__ O4) {
    const int lane = threadIdx.x & 63;
    const int lo = lane & 15, hi = lane >> 4;
    const int wv = threadIdx.x >> 6;
    const int mblk = blockIdx.x % MBLKS;
    const int nspl = blockIdx.x / MBLKS;
    const int mt0 = mblk * 128 + wv * 32;

    const s16x4 bq0 = *(const s16x4*)(KB + (size_t)(mt0 + lo) * 16 + 4 * hi);
    const s16x4 bq1 = *(const s16x4*)(KB + (size_t)(mt0 + 16 + lo) * 16 + 4 * hi);

    f32x4 o0[4], o1[4];
#pragma unroll
    for (int i = 0; i < 4; ++i) {
        o0[i] = (f32x4){0.f, 0.f, 0.f, 0.f};
        o1[i] = (f32x4){0.f, 0.f, 0.f, 0.f};
    }
    attn_core(QB, VT2, bq0, bq1, nspl * (NP / NSPL), lo, hi, o0, o1);

    float* Oc = O4 + (size_t)(nspl & 3) * (NP * 64);
#pragma unroll
    for (int ct = 0; ct < 4; ++ct)
#pragma unroll
        for (int j = 0; j < 4; ++j) {
            atomicAdd(&Oc[(size_t)(mt0 + 4 * hi + j) * 64 + 16 * ct + lo], o0[ct][j]);
            atomicAdd(&Oc[(size_t)(mt0 + 16 + 4 * hi + j) * 64 + 16 * ct + lo], o1[ct][j]);
        }
}

__global__ void epi_atomic_k(const float* __restrict__ O4, const float* __restrict__ xT,
                             const float* __restrict__ gamma, unsigned short* __restrict__ XTP) {
    int m = blockIdx.x * 256 + threadIdx.x;
    if (m >= NP) return;
    int iy = m / WP, ix = m % WP;
    unsigned short* xp = XTP + ((size_t)(iy + 1) * 98 + ix + 1) * 64;
    float den = 0.f;
#pragma unroll
    for (int cp = 0; cp < 4; ++cp) den += O4[(size_t)cp * (NP * 64) + (size_t)m * 64 + 48];
    float rg = gamma[0] / den;
#pragma unroll
    for (int c = 0; c < C; ++c) {
        float o = 0.f;
#pragma unroll
        for (int cp = 0; cp < 4; ++cp) o += O4[(size_t)cp * (NP * 64) + (size_t)m * 64 + c];
        xp[c] = f2bf(rg * o + xT[(size_t)m * 48 + c]);
    }
}

// WB[(ky*4+kx)*48+co][ci64] = bf16(dw[ci][co][ky][kx]), ci>=48 -> 0
__global__ void wprep_k(const float* __restrict__ dw, unsigned short* __restrict__ WB) {
    int idx = blockIdx.x * 256 + threadIdx.x;
    if (idx >= 16 * 48 * 64) return;
    int ci = idx & 63;
    int co = (idx >> 6) % 48;
    int kidx = idx / (48 * 64);
    float v = (ci < C) ? dw[((size_t)ci * C + co) * 16 + kidx] : 0.f;
    WB[idx] = f2bf(v);
}

// ConvTranspose2d via MFMA
__global__ __launch_bounds__(128) void convt_mfma_k(const unsigned short* __restrict__ XTP,
                                                    const unsigned short* __restrict__ WB,
                                                    const float* __restrict__ db,
                                                    float* __restrict__ y) {
    const int lane = threadIdx.x & 63;
    const int lo = lane & 15, hi = lane >> 4;
    const int wv = threadIdx.x >> 6;   // 0..1
    const int b = blockIdx.x;          // 96*2*2
    const int oyp = b >> 2;
    const int py = (b >> 1) & 1;
    const int px = b & 1;

    const int sy[2] = {0, py ? 1 : -1};
    const int kyt[2] = {py ? 2 : 1, py ? 0 : 3};
    const int sx[2] = {0, px ? 1 : -1};
    const int kxt[2] = {px ? 2 : 1, px ? 0 : 3};

    s16x8 bw[2][2][2][3];  // [ty][tx][kk][ct]
#pragma unroll
    for (int ty = 0; ty < 2; ++ty)
#pragma unroll
        for (int tx = 0; tx < 2; ++tx) {
            const unsigned short* wp = WB + (size_t)(kyt[ty] * 4 + kxt[tx]) * 48 * 64;
#pragma unroll
            for (int kk = 0; kk < 2; ++kk)
#pragma unroll
                for (int ct = 0; ct < 3; ++ct)
                    bw[ty][tx][kk][ct] = *(const s16x8*)(wp + (size_t)(ct * 16 + lo) * 64 + kk * 32 + 8 * hi);
        }
    float bias[3];
#pragma unroll
    for (int ct = 0; ct < 3; ++ct) bias[ct] = db[ct * 16 + lo];

    const int oy = 2 * oyp + py;
    for (int i = 0; i < 3; ++i) {
        int ox0 = (wv * 3 + i) * 16;
        f32x4 acc[3];
#pragma unroll
        for (int ct = 0; ct < 3; ++ct) acc[ct] = (f32x4){bias[ct], bias[ct], bias[ct], bias[ct]};
#pragma unroll
        for (int ty = 0; ty < 2; ++ty) {
            int R0 = (oyp + sy[ty] + 1) * 98;
#pragma unroll
            for (int tx = 0; tx < 2; ++tx) {
                const unsigned short* ap = XTP + (size_t)(R0 + ox0 + sx[tx] + 1 + lo) * 64 + 8 * hi;
#pragma unroll
                for (int kk = 0; kk < 2; ++kk) {
                    s16x8 a = *(const s16x8*)(ap + kk * 32);
                    acc[0] = mfma32(a, bw[ty][tx][kk][0], acc[0]);
                    acc[1] = mfma32(a, bw[ty][tx][kk][1], acc[1]);
                    acc[2] = mfma32(a, bw[ty][tx][kk][2], acc[2]);
                }
            }
        }
#pragma unroll
        for (int ct = 0; ct < 3; ++ct)
#pragma unroll
            for (int j = 0; j < 4; ++j)
                y[(size_t)(ct * 16 + lo) * (HH * WW) + oy * WW + 2 * (ox0 + 4 * hi + j) + px] = acc[ct][j];
    }
}

extern "C" void kernel_launch(void* const* d_in, const int* in_sizes, int n_in,
                              void* d_out, int out_size, void* d_ws, size_t ws_size,
                              hipStream_t stream) {
    const float* in    = (const float*)d_in[0];
    const float* qw    = (const float*)d_in[1];
    const float* qb    = (const float*)d_in[2];
    const float* kw    = (const float*)d_in[3];
    const float* kb    = (const float*)d_in[4];
    const float* vw    = (const float*)d_in[5];
    const float* vb    = (const float*)d_in[6];
    const float* gamma = (const float*)d_in[7];
    const float* dw    = (const float*)d_in[8];
    const float* db    = (const float*)d_in[9];
    float* out = (float*)d_out;

    float* ws = (float*)d_ws;
    unsigned short* QB   = (unsigned short*)(ws + OFF_QB);
    unsigned short* KB   = (unsigned short*)(ws + OFF_KB);
    unsigned short* VT2  = (unsigned short*)(ws + OFF_VT2);
    unsigned short* PART = (unsigned short*)(ws + OFF_PART);
    float*          xT   = ws + OFF_XT;
    unsigned short* XTP  = (unsigned short*)(ws + OFF_XTP);
    unsigned short* WB   = (unsigned short*)(ws + OFF_WB);

    pool_k<<<(C * NP + 255) / 256, 256, 0, stream>>>(in, xT);
    qkvprep_k<<<(5 * NP) / 256, 256, 0, stream>>>(xT, qw, qb, kw, kb, vw, vb, QB, KB, VT2);
    hipMemsetAsync(XTP, 0, (size_t)98 * 98 * 64 * sizeof(unsigned short), stream);
    wprep_k<<<(16 * 48 * 64) / 256, 256, 0, stream>>>(dw, WB);

    if (ws_size >= WS_NEED_BYTES) {
        attn_k<<<MBLKS * NSPL, 256, 0, stream>>>(QB, KB, VT2, PART);
        reduce_epi_k<<<288, 256, 0, stream>>>(PART, xT, gamma, XTP);
    } else {
        float* O4 = (float*)PART;   // overlays PART region (9.4 MB < 18.9 MB)
        hipMemsetAsync(O4, 0, (size_t)4 * NP * 64 * sizeof(float), stream);
        attn_atomic_k<<<MBLKS * NSPL, 256, 0, stream>>>(QB, KB, VT2, O4);
        epi_atomic_k<<<(NP + 255) / 256, 256, 0, stream>>>(O4, xT, gamma, XTP);
    }
    convt_mfma_k<<<96 * 2 * 2, 128, 0, stream>>>(XTP, WB, db, out);
}